// Round 1
// baseline (811.383 us; speedup 1.0000x reference)
//
#include <hip/hip_runtime.h>
#include <cstdint>
#include <cstddef>

// LIF recurrent SNN, sinabs-style ThresholdSubtract.
//   B=32 batch rows are independent -> 1 block per batch, state in registers.
//   Spikes are ~4.4 sigma events -> speculate "no spike in chunk", replay on hit.
#define B_       32
#define T_       1000
#define N_       1024
#define THREADS_ 256           // 4 waves; each thread owns 4 consecutive neurons (float4)
#define WAVES_   4
#define CHUNK_   8
#define NCHUNK_  (T_ / CHUNK_) // 125 exactly

// Barrier that only drains LDS (lgkmcnt), NOT vmcnt: keeps the prefetched
// global loads for the next chunk in flight across the per-chunk barrier.
__device__ __forceinline__ void barrier_lds() {
  __asm__ volatile("s_waitcnt lgkmcnt(0)\n\ts_barrier" ::: "memory");
}

__global__ void zero_kernel(float4* __restrict__ out, int n4) {
  int i = blockIdx.x * blockDim.x + threadIdx.x;
  int stride = gridDim.x * blockDim.x;
  float4 z = make_float4(0.f, 0.f, 0.f, 0.f);
  for (; i < n4; i += stride) out[i] = z;
}

__global__ __launch_bounds__(THREADS_, 1)
void lif_main(const float* __restrict__ x, const float* __restrict__ w,
              const float* __restrict__ brec_g, float* __restrict__ out)
{
  const int b    = blockIdx.x;
  const int tid  = threadIdx.x;
  const int lane = tid & 63;
  const int wv   = tid >> 6;
  const int n0   = tid << 2;

  const float* xb   = x   + (size_t)b * T_ * N_ + n0;
  float*       outb = out + (size_t)b * T_ * N_ + n0;

  // Double-buffered (parity) so ONE barrier per chunk/step suffices and no
  // counter resets are needed (masks are written unconditionally).
  __shared__ unsigned long long s_cmask[2][WAVES_]; // per-chunk "any spike" per wave
  __shared__ unsigned long long s_mask [2][WAVES_]; // per-step spike mask per wave (replay)
  __shared__ float4             s_val  [2][THREADS_]; // spike values (replay)

  float4 state = make_float4(0.f, 0.f, 0.f, 0.f);
  float4 rec   = make_float4(0.f, 0.f, 0.f, 0.f);   // initial carry rec = 0 (NOT b_rec)
  const float4 brec = *(const float4*)(brec_g + n0);

  float4 xs[CHUNK_], xn[CHUNK_];
#pragma unroll
  for (int k = 0; k < CHUNK_; ++k)
    xs[k] = *(const float4*)(xb + (size_t)k * N_);

  for (int c = 0; c < NCHUNK_; ++c) {
    // ---- prefetch next chunk's input (loads stay in flight past the barrier) ----
    if (c + 1 < NCHUNK_) {
      const float* xp = xb + (size_t)(c + 1) * CHUNK_ * N_;
#pragma unroll
      for (int k = 0; k < CHUNK_; ++k)
        xn[k] = *(const float4*)(xp + (size_t)k * N_);
    }

    // ---- speculative pass: assume zero spikes in the whole block this chunk ----
    float4 st = state;
    float4 r  = rec;      // incoming rec (may differ from brec if prev chunk spiked)
    int any = 0;
#pragma unroll
    for (int k = 0; k < CHUNK_; ++k) {
      float tx = xs[k].x + r.x, ty = xs[k].y + r.y,
            tz = xs[k].z + r.z, tw = xs[k].w + r.w;
      float ax = (st.x > 0.f) ? floorf(st.x) : 0.f;
      float ay = (st.y > 0.f) ? floorf(st.y) : 0.f;
      float az = (st.z > 0.f) ? floorf(st.z) : 0.f;
      float aw = (st.w > 0.f) ? floorf(st.w) : 0.f;
      any |= (ax != 0.f) | (ay != 0.f) | (az != 0.f) | (aw != 0.f);
      st.x = (st.x - ax) * 0.9f + 0.1f * tx;
      st.y = (st.y - ay) * 0.9f + 0.1f * ty;
      st.z = (st.z - az) * 0.9f + 0.1f * tz;
      st.w = (st.w - aw) * 0.9f + 0.1f * tw;
      r = brec;           // no-spike assumption: rec_{t+1} = 0 @ w^T + b_rec = b_rec
    }

    const int p = c & 1;
    unsigned long long wm = __ballot(any);
    if (lane == 0) s_cmask[p][wv] = wm;
    barrier_lds();
    unsigned long long anyblk =
        s_cmask[p][0] | s_cmask[p][1] | s_cmask[p][2] | s_cmask[p][3];

    if (anyblk == 0ULL) {
      // fast path: no spikes anywhere -> commit; output rows stay zero (pre-zeroed)
      state = st;
      rec   = brec;
    } else {
      // ---- exact replay of the chunk with per-step spike exchange ----
      st = state;
      r  = rec;
#pragma unroll 1
      for (int k = 0; k < CHUNK_; ++k) {
        const int q = k & 1;
        float tx = xs[k].x + r.x, ty = xs[k].y + r.y,
              tz = xs[k].z + r.z, tw = xs[k].w + r.w;
        float ax = (st.x > 0.f) ? floorf(st.x) : 0.f;
        float ay = (st.y > 0.f) ? floorf(st.y) : 0.f;
        float az = (st.z > 0.f) ? floorf(st.z) : 0.f;
        float aw = (st.w > 0.f) ? floorf(st.w) : 0.f;
        int ms = (ax != 0.f) | (ay != 0.f) | (az != 0.f) | (aw != 0.f);
        if (ms) {
          s_val[q][tid] = make_float4(ax, ay, az, aw);
          size_t ot = (size_t)(c * CHUNK_ + k) * N_;
          if (ax != 0.f) outb[ot + 0] = ax;
          if (ay != 0.f) outb[ot + 1] = ay;
          if (az != 0.f) outb[ot + 2] = az;
          if (aw != 0.f) outb[ot + 3] = aw;
        }
        unsigned long long sm = __ballot(ms);
        if (lane == 0) s_mask[q][wv] = sm;
        st.x = (st.x - ax) * 0.9f + 0.1f * tx;
        st.y = (st.y - ay) * 0.9f + 0.1f * ty;
        st.z = (st.z - az) * 0.9f + 0.1f * tz;
        st.w = (st.w - aw) * 0.9f + 0.1f * tw;
        barrier_lds();
        // sparse rank-1 rec update: rec[n] = b_rec[n] + sum_j act[j] * w[n][j]
        float4 racc = brec;
#pragma unroll 1
        for (int w2 = 0; w2 < WAVES_; ++w2) {
          unsigned long long mm = s_mask[q][w2];
          while (mm) {
            int l = __builtin_ctzll(mm);
            mm &= mm - 1;
            int j = (w2 << 6) + l;
            float4 v = s_val[q][j];
            int jn = j << 2;
            if (v.x != 0.f) {
              racc.x += v.x * w[(size_t)(n0 + 0) * N_ + jn];
              racc.y += v.x * w[(size_t)(n0 + 1) * N_ + jn];
              racc.z += v.x * w[(size_t)(n0 + 2) * N_ + jn];
              racc.w += v.x * w[(size_t)(n0 + 3) * N_ + jn];
            }
            if (v.y != 0.f) {
              int j1 = jn + 1;
              racc.x += v.y * w[(size_t)(n0 + 0) * N_ + j1];
              racc.y += v.y * w[(size_t)(n0 + 1) * N_ + j1];
              racc.z += v.y * w[(size_t)(n0 + 2) * N_ + j1];
              racc.w += v.y * w[(size_t)(n0 + 3) * N_ + j1];
            }
            if (v.z != 0.f) {
              int j2 = jn + 2;
              racc.x += v.z * w[(size_t)(n0 + 0) * N_ + j2];
              racc.y += v.z * w[(size_t)(n0 + 1) * N_ + j2];
              racc.z += v.z * w[(size_t)(n0 + 2) * N_ + j2];
              racc.w += v.z * w[(size_t)(n0 + 3) * N_ + j2];
            }
            if (v.w != 0.f) {
              int j3 = jn + 3;
              racc.x += v.w * w[(size_t)(n0 + 0) * N_ + j3];
              racc.y += v.w * w[(size_t)(n0 + 1) * N_ + j3];
              racc.z += v.w * w[(size_t)(n0 + 2) * N_ + j3];
              racc.w += v.w * w[(size_t)(n0 + 3) * N_ + j3];
            }
          }
        }
        r = racc;
      }
      state = st;
      rec   = r;
    }

    // rotate prefetch buffer into place (register moves)
#pragma unroll
    for (int k = 0; k < CHUNK_; ++k) xs[k] = xn[k];
  }
}

extern "C" void kernel_launch(void* const* d_in, const int* in_sizes, int n_in,
                              void* d_out, int out_size, void* d_ws, size_t ws_size,
                              hipStream_t stream) {
  const float* x  = (const float*)d_in[0]; // [B,T,N] input_current
  const float* w  = (const float*)d_in[1]; // [N,N] w_rec (row-major [out,in])
  const float* br = (const float*)d_in[2]; // [N] b_rec
  float* out = (float*)d_out;              // [B,T,N] spikes

  // 1) zero the (mostly-zero) output at full-chip write BW
  int n4 = out_size >> 2; // B*T*N divisible by 4
  zero_kernel<<<4096, 256, 0, stream>>>((float4*)out, n4);

  // 2) sequential LIF scan, one block per batch row
  lif_main<<<B_, THREADS_, 0, stream>>>(x, w, br, out);
}

// Round 2
// 351.354 us; speedup vs baseline: 2.3093x; 2.3093x over previous
//
#include <hip/hip_runtime.h>
#include <cstdint>
#include <cstddef>

// LIF recurrent SNN, sinabs ThresholdSubtract.
//   B=32 independent batch rows -> 1 block per batch, state in registers.
//   Spikes ~4.4 sigma -> speculate "no spike in chunk", exact replay on hit.
//   Round-2: register prefetch FORCED via inline-asm global_load_dwordx4 with
//   hand-placed s_waitcnt vmcnt(N); depth-2 chunk pipeline (16 loads in flight
//   per wave). Round-1's compiler collapsed the C-level prefetch to 32 VGPRs
//   and serialized 8 HBM latencies per chunk (644us, VALUBusy 0.9%).
#define B_       32
#define T_       1000
#define N_       1024
#define THREADS_ 256           // 4 waves; each thread owns 4 consecutive neurons
#define WAVES_   4
#define CHUNK_   8
#define NCHUNK_  (T_ / CHUNK_) // 125 = 3*41 + 2

typedef float v4f __attribute__((ext_vector_type(4)));

// Barrier that drains only LDS (lgkmcnt), NOT vmcnt: prefetched global loads
// stay in flight across the per-chunk spike-exchange barrier.
__device__ __forceinline__ void barrier_lds() {
  __asm__ volatile("s_waitcnt lgkmcnt(0)\n\ts_barrier" ::: "memory");
}

// Issue 8 x global_load_dwordx4 into a register buffer. asm volatile keeps
// them at this program point; results are NOT ready until WAITBUF.
#define ISSUE_CHUNK(buf, base)                                              \
  do {                                                                      \
    _Pragma("unroll")                                                       \
    for (int _k = 0; _k < CHUNK_; ++_k) {                                   \
      const v4f* _p = (const v4f*)((base) + (size_t)_k * N_);               \
      __asm__ volatile("global_load_dwordx4 %0, %1, off"                    \
                       : "=&v"(buf[_k])                                     \
                       : "v"(_p)                                            \
                       : "memory");                                         \
    }                                                                       \
  } while (0)

// Wait until at most IMM vmem ops outstanding; ties the buffer registers as
// read-write operands so no consumer of buf can be scheduled above the wait.
// vmcnt completion is FIFO: <=16 outstanding guarantees the oldest chunk's 8
// loads are complete even when (rare) replay loads/stores are also in flight
// (those are always newer than the buffer being waited on).
#define WAITBUF(buf, IMM)                                                   \
  __asm__ volatile("s_waitcnt vmcnt(" #IMM ")"                              \
                   : "+v"(buf[0]), "+v"(buf[1]), "+v"(buf[2]),              \
                     "+v"(buf[3]), "+v"(buf[4]), "+v"(buf[5]),              \
                     "+v"(buf[6]), "+v"(buf[7])                             \
                   :                                                        \
                   : "memory")

__global__ __launch_bounds__(THREADS_, 1)
void lif_main(const float* __restrict__ x, const float* __restrict__ w,
              const float* __restrict__ brec_g, float* __restrict__ out)
{
  const int b    = blockIdx.x;
  const int tid  = threadIdx.x;
  const int lane = tid & 63;
  const int wv   = tid >> 6;
  const int n0   = tid << 2;

  const float* xb   = x   + (size_t)b * T_ * N_ + n0;
  float*       outb = out + (size_t)b * T_ * N_ + n0;

  // Double-buffered (parity) so ONE barrier per chunk/step suffices and no
  // counter resets are needed (masks are written unconditionally).
  __shared__ unsigned long long s_cmask[2][WAVES_]; // per-chunk any-spike per wave
  __shared__ unsigned long long s_mask [2][WAVES_]; // per-step spike mask (replay)
  __shared__ v4f                s_val  [2][THREADS_]; // spike values (replay)

  v4f state = (v4f)(0.f);
  v4f rec   = (v4f)(0.f);                 // initial carry rec = 0 (NOT b_rec)
  const v4f brec = *(const v4f*)(brec_g + n0);

  // process one 8-step chunk held in register buffer xs
  auto process = [&](const v4f (&xs)[CHUNK_], int c) {
    // ---- speculative pass: assume zero spikes block-wide this chunk ----
    // Spike at step k iff pre-update state >= 1.0; track running max instead
    // of computing floor/select. Update (st-0)*0.9+0.1*t == st*0.9+0.1*t is
    // bit-identical to the validated replay arithmetic with act==0.
    v4f st = state;
    v4f r  = rec;                 // incoming rec (brec unless prev chunk spiked)
    v4f cmax = st;
#pragma unroll
    for (int k = 0; k < CHUNK_; ++k) {
      cmax.x = fmaxf(cmax.x, st.x);
      cmax.y = fmaxf(cmax.y, st.y);
      cmax.z = fmaxf(cmax.z, st.z);
      cmax.w = fmaxf(cmax.w, st.w);
      v4f t = xs[k] + r;
      st = st * 0.9f + 0.1f * t;
      r = brec;                   // no-spike assumption: rec_{t+1} = b_rec
    }
    float m = fmaxf(fmaxf(cmax.x, cmax.y), fmaxf(cmax.z, cmax.w));
    int any = (m >= 1.0f);

    const int p = c & 1;
    unsigned long long wm = __ballot(any);
    if (lane == 0) s_cmask[p][wv] = wm;
    barrier_lds();
    unsigned long long anyblk =
        s_cmask[p][0] | s_cmask[p][1] | s_cmask[p][2] | s_cmask[p][3];

    if (anyblk == 0ULL) {
      state = st;                 // fast path: commit; output rows stay zero
      rec   = brec;
      return;
    }

    // ---- exact replay of the chunk with per-step spike exchange ----
    st = state;
    r  = rec;
#pragma unroll 1
    for (int k = 0; k < CHUNK_; ++k) {
      const int q = k & 1;
      float tx = xs[k].x + r.x, ty = xs[k].y + r.y,
            tz = xs[k].z + r.z, tw = xs[k].w + r.w;
      float ax = (st.x > 0.f) ? floorf(st.x) : 0.f;
      float ay = (st.y > 0.f) ? floorf(st.y) : 0.f;
      float az = (st.z > 0.f) ? floorf(st.z) : 0.f;
      float aw = (st.w > 0.f) ? floorf(st.w) : 0.f;
      int ms = (ax != 0.f) | (ay != 0.f) | (az != 0.f) | (aw != 0.f);
      if (ms) {
        v4f v; v.x = ax; v.y = ay; v.z = az; v.w = aw;
        s_val[q][tid] = v;
        size_t ot = (size_t)(c * CHUNK_ + k) * N_;
        if (ax != 0.f) outb[ot + 0] = ax;
        if (ay != 0.f) outb[ot + 1] = ay;
        if (az != 0.f) outb[ot + 2] = az;
        if (aw != 0.f) outb[ot + 3] = aw;
      }
      unsigned long long sm = __ballot(ms);
      if (lane == 0) s_mask[q][wv] = sm;
      st.x = (st.x - ax) * 0.9f + 0.1f * tx;
      st.y = (st.y - ay) * 0.9f + 0.1f * ty;
      st.z = (st.z - az) * 0.9f + 0.1f * tz;
      st.w = (st.w - aw) * 0.9f + 0.1f * tw;
      barrier_lds();
      // sparse rank-1 rec update: rec[n] = b_rec[n] + sum_j act[j]*w[n][j]
      v4f racc = brec;
#pragma unroll 1
      for (int w2 = 0; w2 < WAVES_; ++w2) {
        unsigned long long mm = s_mask[q][w2];
        while (mm) {
          int l = __builtin_ctzll(mm);
          mm &= mm - 1;
          int j = (w2 << 6) + l;
          v4f v = s_val[q][j];
          int jn = j << 2;
          if (v.x != 0.f) {
            racc.x += v.x * w[(size_t)(n0 + 0) * N_ + jn];
            racc.y += v.x * w[(size_t)(n0 + 1) * N_ + jn];
            racc.z += v.x * w[(size_t)(n0 + 2) * N_ + jn];
            racc.w += v.x * w[(size_t)(n0 + 3) * N_ + jn];
          }
          if (v.y != 0.f) {
            int j1 = jn + 1;
            racc.x += v.y * w[(size_t)(n0 + 0) * N_ + j1];
            racc.y += v.y * w[(size_t)(n0 + 1) * N_ + j1];
            racc.z += v.y * w[(size_t)(n0 + 2) * N_ + j1];
            racc.w += v.y * w[(size_t)(n0 + 3) * N_ + j1];
          }
          if (v.z != 0.f) {
            int j2 = jn + 2;
            racc.x += v.z * w[(size_t)(n0 + 0) * N_ + j2];
            racc.y += v.z * w[(size_t)(n0 + 1) * N_ + j2];
            racc.z += v.z * w[(size_t)(n0 + 2) * N_ + j2];
            racc.w += v.z * w[(size_t)(n0 + 3) * N_ + j2];
          }
          if (v.w != 0.f) {
            int j3 = jn + 3;
            racc.x += v.w * w[(size_t)(n0 + 0) * N_ + j3];
            racc.y += v.w * w[(size_t)(n0 + 1) * N_ + j3];
            racc.z += v.w * w[(size_t)(n0 + 2) * N_ + j3];
            racc.w += v.w * w[(size_t)(n0 + 3) * N_ + j3];
          }
        }
      }
      r = racc;
    }
    state = st;
    rec   = r;
  };

  // ---- depth-2 modulo-scheduled chunk pipeline over 3 register buffers ----
  v4f bufA[CHUNK_], bufB[CHUNK_], bufC[CHUNK_];
  ISSUE_CHUNK(bufA, xb);
  ISSUE_CHUNK(bufB, xb + (size_t)CHUNK_ * N_);

  int c = 0;
#pragma unroll 1
  for (int t3 = 0; t3 < 41; ++t3) {   // 41 triples = chunks 0..122
    ISSUE_CHUNK(bufC, xb + (size_t)(c + 2) * CHUNK_ * N_);
    WAITBUF(bufA, 16);
    process(bufA, c); ++c;
    ISSUE_CHUNK(bufA, xb + (size_t)(c + 2) * CHUNK_ * N_);
    WAITBUF(bufB, 16);
    process(bufB, c); ++c;
    ISSUE_CHUNK(bufB, xb + (size_t)(c + 2) * CHUNK_ * N_);
    WAITBUF(bufC, 16);
    process(bufC, c); ++c;
  }
  // tail: chunks 123 (bufA) and 124 (bufB) already issued
  WAITBUF(bufA, 8);
  process(bufA, 123);
  WAITBUF(bufB, 0);
  process(bufB, 124);
}

extern "C" void kernel_launch(void* const* d_in, const int* in_sizes, int n_in,
                              void* d_out, int out_size, void* d_ws, size_t ws_size,
                              hipStream_t stream) {
  const float* x  = (const float*)d_in[0]; // [B,T,N] input_current
  const float* w  = (const float*)d_in[1]; // [N,N] w_rec (row-major [out,in])
  const float* br = (const float*)d_in[2]; // [N] b_rec
  float* out = (float*)d_out;              // [B,T,N] spikes

  // 1) zero the (mostly-zero) output: graph-capturable memset node, full BW
  hipMemsetAsync(out, 0, (size_t)out_size * sizeof(float), stream);

  // 2) sequential LIF scan, one block per batch row
  lif_main<<<B_, THREADS_, 0, stream>>>(x, w, br, out);
}